// Round 18
// baseline (181.283 us; speedup 1.0000x reference)
//
#include <hip/hip_runtime.h>
#include <math.h>

#define NPTS 8192
#define KNN 40
#define DD 32
#define CIN 16
#define RPB 8        // rows per block (32 threads per row)
#define QT 1024      // kNN LDS tile (points)
#define NT8 (NPTS / QT)

// ---- ws layout (float offsets) ----
#define OFF_H      0u         // 8192*32
#define OFF_XIN    262144u    // 8192*32
#define OFF_HL     524288u    // 8192*32
#define OFF_SL     786432u    // 8192*4 (float4: s0,s1,s2, 0.5*|s|^2)
#define OFF_ESQ    819200u    // 8192*40
#define OFF_O      1146880u   // 8192*32
#define OFF_IDX    1409024u   // 8192*40 (int)
#define OFF_SUMD   1736704u   // 8192
#define OFF_INDEG  1744896u   // 8192
#define OFF_STATS  1753088u   // 130 slots x 32-float stride (1 line/slot)
#define ZERO_FLOATS (8192u + 8192u + 130u * 32u)

#define ST(i) stats[(i) * 32]

__device__ __forceinline__ float elu_f(float x) { return x > 0.f ? x : (expf(x) - 1.f); }

__device__ __forceinline__ float grp_sum32(float v) {
#pragma unroll
    for (int m = 1; m < 32; m <<= 1) v += __shfl_xor(v, m);
    return v;
}

__device__ __forceinline__ float rfl(float v) {
    return __int_as_float(__builtin_amdgcn_readfirstlane(__float_as_int(v)));
}

// order-preserving float->uint key
__device__ __forceinline__ unsigned fkey(float x) {
    unsigned b = __float_as_uint(x);
    return b ^ ((unsigned)((int)b >> 31) | 0x80000000u);
}
__device__ __forceinline__ float kinv(unsigned k) {
    unsigned b = (k & 0x80000000u) ? (k ^ 0x80000000u) : ~k;
    return __uint_as_float(b);
}

// kth-smallest of the 256 values {u0..u3} x 64 lanes, exact
__device__ __forceinline__ unsigned bisect_kth4(unsigned u0, unsigned u1,
    unsigned u2, unsigned u3, int kth) {
    unsigned lo = 0u, hi = 0xFFFFFFFFu;
    while (lo < hi) {
        unsigned mid = lo + ((hi - lo) >> 1);
        int cnt = __popcll(__ballot(u0 <= mid)) + __popcll(__ballot(u1 <= mid))
                + __popcll(__ballot(u2 <= mid)) + __popcll(__ballot(u3 <= mid));
        if (cnt >= kth) hi = mid; else lo = mid + 1;
    }
    return hi;
}

// ---------- K1: pre-MLP + BN1 stats (32 thr/row, 1 ch/thr) ----------
__global__ __launch_bounds__(256) void k_pre(const float* __restrict__ x,
    const float* __restrict__ w1, const float* __restrict__ b1,
    const float* __restrict__ w2, const float* __restrict__ b2,
    float* __restrict__ h, float* __restrict__ stats)
{
    __shared__ float sw1[CIN * DD], sw2[DD * DD], sb1[DD], sb2[DD];
    __shared__ float bufx[RPB][20], buft[RPB][36];
    __shared__ float sstat[2 * DD];
    int tid = threadIdx.x;
    for (int t = tid; t < CIN * DD; t += 256) sw1[t] = w1[t];
    for (int t = tid; t < DD * DD; t += 256) sw2[t] = w2[t];
    if (tid < DD) { sb1[tid] = b1[tid]; sb2[tid] = b2[tid]; }
    if (tid < 2 * DD) sstat[tid] = 0.f;

    int r = tid >> 5, ch = tid & 31;
    int g = blockIdx.x * RPB + r;
    if (ch < CIN) bufx[r][ch] = x[(size_t)g * CIN + ch];
    __syncthreads();

    float acc = sb1[ch];
#pragma unroll
    for (int k4 = 0; k4 < CIN; k4 += 4) {
        float4 v = *(const float4*)&bufx[r][k4];
        acc = fmaf(v.x, sw1[(k4 + 0) * DD + ch], acc);
        acc = fmaf(v.y, sw1[(k4 + 1) * DD + ch], acc);
        acc = fmaf(v.z, sw1[(k4 + 2) * DD + ch], acc);
        acc = fmaf(v.w, sw1[(k4 + 3) * DD + ch], acc);
    }
    acc = elu_f(acc);
    buft[r][ch] = acc;
    __syncthreads();

    float o = sb2[ch];
#pragma unroll
    for (int k4 = 0; k4 < DD; k4 += 4) {
        float4 v = *(const float4*)&buft[r][k4];
        o = fmaf(v.x, sw2[(k4 + 0) * DD + ch], o);
        o = fmaf(v.y, sw2[(k4 + 1) * DD + ch], o);
        o = fmaf(v.z, sw2[(k4 + 2) * DD + ch], o);
        o = fmaf(v.w, sw2[(k4 + 3) * DD + ch], o);
    }
    o = elu_f(o);
    h[(size_t)g * DD + ch] = o;

    float s = o + __shfl_xor(o, 32);
    float q = o * o;
    q += __shfl_xor(q, 32);
    if ((tid & 32) == 0) { atomicAdd(&sstat[ch], s); atomicAdd(&sstat[DD + ch], q); }
    __syncthreads();
    if (tid < 2 * DD) atomicAdd(&ST(tid), sstat[tid]);
}

// ---------- K2: BN1 apply + h_l/s_l projections (32 thr/row) ----------
__global__ __launch_bounds__(256) void k_proj(const float* __restrict__ h,
    const float* __restrict__ stats,
    const float* __restrict__ g1, const float* __restrict__ b1g,
    const float* __restrict__ hw, const float* __restrict__ hb,
    const float* __restrict__ sw,
    float* __restrict__ xin, float* __restrict__ hl, float4* __restrict__ sl4)
{
    __shared__ float shw[DD * DD], ssw[DD * 3], sa[DD], sbp[DD], shb[DD];
    __shared__ float rrow[RPB][36];
    int tid = threadIdx.x;
    for (int t = tid; t < DD * DD; t += 256) shw[t] = hw[t];
    if (tid < DD * 3) ssw[tid] = sw[tid];
    if (tid < DD) {
        float mean = ST(tid) * (1.f / NPTS);
        float var = ST(32 + tid) * (1.f / NPTS) - mean * mean;
        float a = g1[tid] * rsqrtf(var + 1e-5f);
        sa[tid] = a;
        sbp[tid] = b1g[tid] - a * mean;
        shb[tid] = hb[tid];
    }
    __syncthreads();

    int r = tid >> 5, ch = tid & 31;
    int g = blockIdx.x * RPB + r;

    float v = fmaf(sa[ch], h[(size_t)g * DD + ch], sbp[ch]);
    xin[(size_t)g * DD + ch] = v;
    rrow[r][ch] = v;

    float p0 = v * ssw[ch * 3 + 0];
    float p1 = v * ssw[ch * 3 + 1];
    float p2 = v * ssw[ch * 3 + 2];
    p0 = grp_sum32(p0); p1 = grp_sum32(p1); p2 = grp_sum32(p2);
    if (ch == 0) sl4[g] = make_float4(p0, p1, p2, 0.5f * (p0 * p0 + p1 * p1 + p2 * p2));
    __syncthreads();

    float o = shb[ch];
#pragma unroll
    for (int k4 = 0; k4 < DD; k4 += 4) {
        float4 vv = *(const float4*)&rrow[r][k4];
        o = fmaf(vv.x, shw[(k4 + 0) * DD + ch], o);
        o = fmaf(vv.y, shw[(k4 + 1) * DD + ch], o);
        o = fmaf(vv.z, shw[(k4 + 2) * DD + ch], o);
        o = fmaf(vv.w, shw[(k4 + 3) * DD + ch], o);
    }
    hl[(size_t)g * DD + ch] = o;
}

// ---------- K3: kNN — single-pass per-lane top-4 + register emit ----------
// 1 query/wave, 8 waves/block, DMA-staged LDS tiles (32KB dbuf, 4 blk/CU).
// Each lane keeps sorted top-4 (e,idx) + e5 (5th smallest seen). Exact 40th
// via 4-reg bisect; emit from registers. If any lane evicted a value <= thr
// (P~0.3%/query) -> exact wave-sorted fallback rebuild from global (r2 alg).
__device__ __forceinline__ void emit_one(unsigned u, int j, float qw,
    unsigned thr, int nlt, int need, int prelt, int preeq,
    unsigned long long mlt, unsigned long long meq, unsigned long long ltm,
    int rb, int* __restrict__ idxo, float* __restrict__ esq,
    float* __restrict__ sumd, float* __restrict__ indeg)
{
    int pos = -1;
    if (u < thr) pos = prelt + __popcll(mlt & ltm);
    else if (u == thr) {
        int rk = preeq + __popcll(meq & ltm);
        if (rk < need) pos = nlt + rk;
    }
    if (pos >= 0) {
        float e = kinv(u);
        float d2 = fmaxf(2.f * (e + qw), 0.f);
        idxo[rb + pos] = j; esq[rb + pos] = d2;
        float dist = sqrtf(d2 + 1e-6f);
        atomicAdd(&sumd[j], dist); atomicAdd(&indeg[j], 1.f);
    }
}

typedef __attribute__((address_space(1))) const unsigned glds_src_t;
typedef __attribute__((address_space(3))) unsigned glds_dst_t;

#define EDQ(p, ex, ey, ez) fmaf(-(ex), (p).x, fmaf(-(ey), (p).y, fmaf(-(ez), (p).z, (p).w)))

// exact fallback: r2-style lane-sorted top-40 rebuild from global (e-space)
__device__ void knn_fallback(const float4* __restrict__ sl4, int qi,
    float qx, float qy, float qz, float qw_, int lane,
    int* __restrict__ idxo, float* __restrict__ esq,
    float* __restrict__ sumd, float* __restrict__ indeg)
{
    float h_d = INFINITY;   // sorted ascending across lanes 0..39
    int   h_i = 0;
    float gate = INFINITY;

    for (int base = 0; base < NPTS; base += 64) {
        int j = base + lane;
        float4 p = sl4[j];
        float e = EDQ(p, qx, qy, qz);
        if (j == qi) e = INFINITY;
        unsigned long long m = __ballot(e < gate);
        while (m) {
            int src = __ffsll(m) - 1;
            m &= m - 1;
            float db = __shfl(e, src);
            if (db < gate) {
                unsigned long long pm = __ballot(db < h_d) & 0xFFFFFFFFFFull;
                if (pm) {
                    int jb = base + src;
                    int pos = __ffsll(pm) - 1;
                    float sh = __shfl_up(h_d, 1);
                    int   si = __shfl_up(h_i, 1);
                    bool seg = (lane > pos) && (lane < KNN);
                    h_d = (lane == pos) ? db : (seg ? sh : h_d);
                    h_i = (lane == pos) ? jb : (seg ? si : h_i);
                    gate = __shfl(h_d, KNN - 1);
                }
            }
        }
    }
    if (lane < KNN) {
        int rb = qi * KNN + lane;
        float d2 = fmaxf(2.f * (h_d + qw_), 0.f);
        idxo[rb] = h_i;
        esq[rb] = d2;
        float dist = sqrtf(d2 + 1e-6f);
        atomicAdd(&sumd[h_i], dist);
        atomicAdd(&indeg[h_i], 1.f);
    }
}

__global__ __launch_bounds__(512, 8) void k_knn(const float4* __restrict__ sl4,
    int* __restrict__ idxo, float* __restrict__ esq,
    float* __restrict__ sumd, float* __restrict__ indeg)
{
    __shared__ float4 tile[2][QT];
    int tid = threadIdx.x, lane = tid & 63, w = tid >> 6;
    int qi = blockIdx.x * 8 + w;       // 1 query per wave
    float4 q4 = sl4[qi];
    float qx = rfl(q4.x), qy = rfl(q4.y), qz = rfl(q4.z), qw_ = rfl(q4.w);

    // stage tile t into tile[b]: 2 async 1KB wave-DMAs per wave
#define STAGE(t, b) { \
    _Pragma("unroll") \
    for (int c = 0; c < 2; ++c) { \
        int off = w * 128 + c * 64; \
        __builtin_amdgcn_global_load_lds( \
            (glds_src_t*)(sl4 + (t) * QT + off + lane), \
            (glds_dst_t*)&tile[b][off], 16, 0, 0); \
    } }

    float e0 = INFINITY, e1 = INFINITY, e2 = INFINITY, e3 = INFINITY, e5 = INFINITY;
    int j0 = -1, j1 = -1, j2 = -1, j3 = -1;

    STAGE(0, 0)
    __syncthreads();
    for (int t = 0; t < NT8; ++t) {
        if (t + 1 < NT8) STAGE(t + 1, (t + 1) & 1)
        const float4* tp = tile[t & 1];
        int tb = t * QT;
#pragma unroll 4
        for (int i = 0; i < QT / 64; ++i) {
            float4 p = tp[i * 64 + lane];
            float e = EDQ(p, qx, qy, qz);
            e5 = fminf(e5, fmaxf(e, e3));
            if (e < e3) {                      // sorted insert (value+idx)
                e3 = e; j3 = tb + i * 64 + lane;
                if (e3 < e2) {
                    float tv = e2; e2 = e3; e3 = tv;
                    int tj = j2; j2 = j3; j3 = tj;
                    if (e2 < e1) {
                        tv = e1; e1 = e2; e2 = tv;
                        tj = j1; j1 = j2; j2 = tj;
                        if (e1 < e0) {
                            tv = e0; e0 = e1; e1 = tv;
                            tj = j0; j0 = j1; j1 = tj;
                        }
                    }
                }
            }
        }
        __syncthreads();
    }

    // drop self (global min of e -> always captured in some lane's regs)
    float f0 = (j0 == qi) ? INFINITY : e0;
    float f1 = (j1 == qi) ? INFINITY : e1;
    float f2 = (j2 == qi) ? INFINITY : e2;
    float f3 = (j3 == qi) ? INFINITY : e3;
    unsigned u0 = fkey(f0), u1 = fkey(f1), u2 = fkey(f2), u3 = fkey(f3);
    unsigned thr = bisect_kth4(u0, u1, u2, u3, KNN);

    // miss check: did any lane evict a value that could be in the top-40?
    bool miss = __ballot(fkey(e5) <= thr) != 0ull;
    if (!miss) {
        unsigned long long ltm = (1ull << lane) - 1;
        unsigned long long mlt0 = __ballot(u0 < thr), mlt1 = __ballot(u1 < thr);
        unsigned long long mlt2 = __ballot(u2 < thr), mlt3 = __ballot(u3 < thr);
        unsigned long long meq0 = __ballot(u0 == thr), meq1 = __ballot(u1 == thr);
        unsigned long long meq2 = __ballot(u2 == thr), meq3 = __ballot(u3 == thr);
        int n0 = __popcll(mlt0), n1 = __popcll(mlt1), n2 = __popcll(mlt2), n3 = __popcll(mlt3);
        int q0c = __popcll(meq0), q1c = __popcll(meq1), q2c = __popcll(meq2);
        int nlt = n0 + n1 + n2 + n3;
        int need = KNN - nlt;
        int rb = qi * KNN;
        emit_one(u0, j0, qw_, thr, nlt, need, 0, 0, mlt0, meq0, ltm, rb, idxo, esq, sumd, indeg);
        emit_one(u1, j1, qw_, thr, nlt, need, n0, q0c, mlt1, meq1, ltm, rb, idxo, esq, sumd, indeg);
        emit_one(u2, j2, qw_, thr, nlt, need, n0 + n1, q0c + q1c, mlt2, meq2, ltm, rb, idxo, esq, sumd, indeg);
        emit_one(u3, j3, qw_, thr, nlt, need, n0 + n1 + n2, q0c + q1c + q2c, mlt3, meq3, ltm, rb, idxo, esq, sumd, indeg);
    } else {
        knn_fallback(sl4, qi, qx, qy, qz, qw_, lane, idxo, esq, sumd, indeg);
    }
}

// ---------- K4: gather + lin + post-MLP + BN2 stats + losses (32 thr/row) ----
__global__ __launch_bounds__(256) void k_agg(
    const int* __restrict__ idx, const float* __restrict__ esq,
    const float* __restrict__ hl, const float* __restrict__ xin,
    const float4* __restrict__ sl4,
    const float* __restrict__ sumd, const float* __restrict__ indeg,
    const float* __restrict__ lw, const float* __restrict__ lb,
    const float* __restrict__ pw1, const float* __restrict__ pb1,
    const float* __restrict__ pw2, const float* __restrict__ pb2,
    float* __restrict__ o, float* __restrict__ stats)
{
    __shared__ float slw[96 * DD], spw1[67 * DD], spw2[DD * DD];
    __shared__ float slb[DD], spb1[DD], spb2[DD];
    __shared__ float rbuf[RPB][100];
    __shared__ float rb2[RPB][68];
    __shared__ float sstat[2 * DD];
    __shared__ float sl1, sl2;
    int tid = threadIdx.x;
    for (int t = tid; t < 96 * DD; t += 256) slw[t] = lw[t];
    for (int t = tid; t < 67 * DD; t += 256) spw1[t] = pw1[t];
    for (int t = tid; t < DD * DD; t += 256) spw2[t] = pw2[t];
    if (tid < DD) { slb[tid] = lb[tid]; spb1[tid] = pb1[tid]; spb2[tid] = pb2[tid]; }
    if (tid < 2 * DD) sstat[tid] = 0.f;
    if (tid == 254) sl1 = 0.f;
    if (tid == 255) sl2 = 0.f;

    int r = tid >> 5, ch = tid & 31;
    int g = blockIdx.x * RPB + r;
    int rb = g * KNN;
    int half = tid & 32;

    int   idx_c = idx[rb + ch];
    float esq_c = esq[rb + ch];
    int   idx_h = 0; float esq_h = 0.f;
    if (ch < KNN - 32) { idx_h = idx[rb + 32 + ch]; esq_h = esq[rb + 32 + ch]; }

    float sv = 0.f, mv = -INFINITY;
#pragma unroll
    for (int k = 0; k < KNN; ++k) {
        int j   = (k < 32) ? __shfl(idx_c, half | k) : __shfl(idx_h, half | (k - 32));
        float w = (k < 32) ? __shfl(esq_c, half | k) : __shfl(esq_h, half | (k - 32));
        float m = hl[(size_t)j * DD + ch] * w;
        sv += m;
        mv = fmaxf(mv, m);
    }
    rbuf[r][ch] = sv * (1.f / KNN);
    rbuf[r][32 + ch] = mv;
    rbuf[r][64 + ch] = xin[(size_t)g * DD + ch];
    if (ch == 0) { float4 s = sl4[g]; rbuf[r][96] = s.x; rbuf[r][97] = s.y; rbuf[r][98] = s.z; }
    __syncthreads();

    float l2 = 0.f;
    {
        float dist = sqrtf(esq_c + 1e-6f);
        float sd = sumd[idx_c];
        float r1 = 1.f / (sd + 1e-4f);
        float dg = sd * r1 + 1e-4f;
        float df = dist * r1 - dist / dg;
        l2 = df * df;
        if (ch < KNN - 32) {
            dist = sqrtf(esq_h + 1e-6f);
            sd = sumd[idx_h];
            r1 = 1.f / (sd + 1e-4f);
            dg = sd * r1 + 1e-4f;
            df = dist * r1 - dist / dg;
            l2 += df * df;
        }
    }
    l2 = grp_sum32(l2);
    if (ch == 0) {
        float id = indeg[g], sdg = sumd[g];
        float av = id > 0.f ? sdg / fmaxf(id, 1.f) : 0.f;
        float dd = av - 0.5f;
        atomicAdd(&sl2, l2);
        atomicAdd(&sl1, dd * dd);
    }

    float acc = slb[ch];
#pragma unroll
    for (int k4 = 0; k4 < 96; k4 += 4) {
        float4 v = *(const float4*)&rbuf[r][k4];
        acc = fmaf(v.x, slw[(k4 + 0) * DD + ch], acc);
        acc = fmaf(v.y, slw[(k4 + 1) * DD + ch], acc);
        acc = fmaf(v.z, slw[(k4 + 2) * DD + ch], acc);
        acc = fmaf(v.w, slw[(k4 + 3) * DD + ch], acc);
    }
    rb2[r][ch] = acc;
    __syncthreads();

    acc = spb1[ch];
#pragma unroll
    for (int k4 = 0; k4 < DD; k4 += 4) {
        float4 v = *(const float4*)&rb2[r][k4];
        acc = fmaf(v.x, spw1[(k4 + 0) * DD + ch], acc);
        acc = fmaf(v.y, spw1[(k4 + 1) * DD + ch], acc);
        acc = fmaf(v.z, spw1[(k4 + 2) * DD + ch], acc);
        acc = fmaf(v.w, spw1[(k4 + 3) * DD + ch], acc);
    }
#pragma unroll
    for (int s2 = 0; s2 < 3; ++s2)
        acc = fmaf(rbuf[r][96 + s2], spw1[(32 + s2) * DD + ch], acc);
#pragma unroll
    for (int k4 = 0; k4 < DD; k4 += 4) {
        float4 v = *(const float4*)&rbuf[r][64 + k4];
        acc = fmaf(v.x, spw1[(35 + k4 + 0) * DD + ch], acc);
        acc = fmaf(v.y, spw1[(35 + k4 + 1) * DD + ch], acc);
        acc = fmaf(v.z, spw1[(35 + k4 + 2) * DD + ch], acc);
        acc = fmaf(v.w, spw1[(35 + k4 + 3) * DD + ch], acc);
    }
    acc = elu_f(acc);
    rb2[r][32 + ch] = acc;
    __syncthreads();

    acc = spb2[ch];
#pragma unroll
    for (int k4 = 0; k4 < DD; k4 += 4) {
        float4 v = *(const float4*)&rb2[r][32 + k4];
        acc = fmaf(v.x, spw2[(k4 + 0) * DD + ch], acc);
        acc = fmaf(v.y, spw2[(k4 + 1) * DD + ch], acc);
        acc = fmaf(v.z, spw2[(k4 + 2) * DD + ch], acc);
        acc = fmaf(v.w, spw2[(k4 + 3) * DD + ch], acc);
    }
    acc = elu_f(acc);
    o[(size_t)g * DD + ch] = acc;

    float s = acc + __shfl_xor(acc, 32);
    float q = acc * acc;
    q += __shfl_xor(q, 32);
    if ((tid & 32) == 0) { atomicAdd(&sstat[ch], s); atomicAdd(&sstat[DD + ch], q); }
    __syncthreads();
    if (tid < 2 * DD) atomicAdd(&ST(64 + tid), sstat[tid]);
    if (tid == 0) { atomicAdd(&ST(128), sl1); atomicAdd(&ST(129), sl2); }
}

// ---------- K5: BN2 apply (float4) + loss writes ----------
__global__ __launch_bounds__(256) void k_out(const float* __restrict__ o,
    const float* __restrict__ stats, const float* __restrict__ g,
    const float* __restrict__ b, float* __restrict__ dout)
{
    __shared__ float sa[DD], sb[DD];
    int tid = threadIdx.x;
    if (tid < DD) {
        float mean = ST(64 + tid) * (1.f / NPTS);
        float var = ST(96 + tid) * (1.f / NPTS) - mean * mean;
        float a = g[tid] * rsqrtf(var + 1e-5f);
        sa[tid] = a;
        sb[tid] = b[tid] - a * mean;
    }
    __syncthreads();

    int t = blockIdx.x * 256 + tid;
    float4 v = ((const float4*)o)[t];
    int cbase = (t * 4) & (DD - 1);
    float4 rr;
    rr.x = fmaf(sa[cbase + 0], v.x, sb[cbase + 0]);
    rr.y = fmaf(sa[cbase + 1], v.y, sb[cbase + 1]);
    rr.z = fmaf(sa[cbase + 2], v.z, sb[cbase + 2]);
    rr.w = fmaf(sa[cbase + 3], v.w, sb[cbase + 3]);
    ((float4*)dout)[t] = rr;

    if (blockIdx.x == 0) {
        if (tid == DD)     dout[NPTS * DD]     = 0.01f * ST(128) * (1.f / NPTS);
        if (tid == DD + 1) dout[NPTS * DD + 1] = 0.1f  * ST(129) * (1.f / ((float)NPTS * KNN));
    }
}

extern "C" void kernel_launch(void* const* d_in, const int* in_sizes, int n_in,
                              void* d_out, int out_size, void* d_ws, size_t ws_size,
                              hipStream_t stream)
{
    (void)in_sizes; (void)n_in; (void)out_size; (void)ws_size;
    const float* x      = (const float*)d_in[0];
    const float* pre_w1 = (const float*)d_in[5];
    const float* pre_b1 = (const float*)d_in[6];
    const float* pre_w2 = (const float*)d_in[7];
    const float* pre_b2 = (const float*)d_in[8];
    const float* bn1_g  = (const float*)d_in[9];
    const float* bn1_b  = (const float*)d_in[10];
    const float* lin_s_w = (const float*)d_in[11];
    const float* lin_h_w = (const float*)d_in[12];
    const float* lin_h_b = (const float*)d_in[13];
    const float* lin_w   = (const float*)d_in[14];
    const float* lin_b   = (const float*)d_in[15];
    const float* post_w1 = (const float*)d_in[16];
    const float* post_b1 = (const float*)d_in[17];
    const float* post_w2 = (const float*)d_in[18];
    const float* post_b2 = (const float*)d_in[19];
    const float* bn2_g   = (const float*)d_in[20];
    const float* bn2_b   = (const float*)d_in[21];

    float* W = (float*)d_ws;
    float* h     = W + OFF_H;
    float* xin   = W + OFF_XIN;
    float* hl    = W + OFF_HL;
    float4* sl4  = (float4*)(W + OFF_SL);
    float* esq   = W + OFF_ESQ;
    float* o     = W + OFF_O;
    int*   idx   = (int*)(W + OFF_IDX);
    float* sumd  = W + OFF_SUMD;
    float* indeg = W + OFF_INDEG;
    float* stats = W + OFF_STATS;
    float* dout  = (float*)d_out;

    hipMemsetAsync(W + OFF_SUMD, 0, ZERO_FLOATS * sizeof(float), stream);

    k_pre<<<NPTS / RPB, 256, 0, stream>>>(x, pre_w1, pre_b1, pre_w2, pre_b2, h, stats);
    k_proj<<<NPTS / RPB, 256, 0, stream>>>(h, stats, bn1_g, bn1_b,
                                           lin_h_w, lin_h_b, lin_s_w, xin, hl, sl4);
    k_knn<<<NPTS / 8, 512, 0, stream>>>(sl4, idx, esq, sumd, indeg);
    k_agg<<<NPTS / RPB, 256, 0, stream>>>(idx, esq, hl, xin, sl4, sumd, indeg,
                                          lin_w, lin_b, post_w1, post_b1, post_w2, post_b2,
                                          o, stats);
    k_out<<<NPTS * DD / 1024, 256, 0, stream>>>(o, stats, bn2_g, bn2_b, dout);
}

// Round 19
// 120.687 us; speedup vs baseline: 1.5021x; 1.5021x over previous
//
#include <hip/hip_runtime.h>
#include <math.h>

#define NPTS 8192
#define KNN 40
#define DD 32
#define CIN 16
#define RPB 8        // rows per block (32 threads per row)
#define QT 2048      // kNN LDS quarter (points)
#define NQTR 4
#define KQPB 16      // kNN queries per block (2 per wave, 8 waves)
#define CAP 96       // kNN candidate buffer per query

// ---- ws layout (float offsets) ----
#define OFF_H      0u         // 8192*32
#define OFF_XIN    262144u    // 8192*32
#define OFF_HL     524288u    // 8192*32
#define OFF_SL     786432u    // 8192*4 (float4: s0,s1,s2, 0.5*|s|^2)
#define OFF_ESQ    819200u    // 8192*40
#define OFF_O      1146880u   // 8192*32
#define OFF_IDX    1409024u   // 8192*40 (int)
#define OFF_SUMD   1736704u   // 8192
#define OFF_INDEG  1744896u   // 8192
#define OFF_STATS  1753088u   // 130 slots x 32-float stride (1 line/slot)
#define ZERO_FLOATS (8192u + 8192u + 130u * 32u)

// slot map: 0..31 bn1 sum, 32..63 bn1 sq, 64..95 bn2 sum, 96..127 bn2 sq,
//           128 loss1, 129 loss2
#define ST(i) stats[(i) * 32]

__device__ __forceinline__ float elu_f(float x) { return x > 0.f ? x : (expf(x) - 1.f); }

__device__ __forceinline__ float grp_sum32(float v) {
#pragma unroll
    for (int m = 1; m < 32; m <<= 1) v += __shfl_xor(v, m);
    return v;
}

// wave-uniform float -> SGPR
__device__ __forceinline__ float rfl(float v) {
    return __int_as_float(__builtin_amdgcn_readfirstlane(__float_as_int(v)));
}

// order-preserving float->uint key
__device__ __forceinline__ unsigned fkey(float x) {
    unsigned b = __float_as_uint(x);
    return b ^ ((unsigned)((int)b >> 31) | 0x80000000u);
}
__device__ __forceinline__ float kinv(unsigned k) {
    unsigned b = (k & 0x80000000u) ? (k ^ 0x80000000u) : ~k;
    return __uint_as_float(b);
}

// kth-smallest (1-based) of the 128 values {u0,u1} x 64 lanes, exact
__device__ __forceinline__ unsigned bisect_kth(unsigned u0, unsigned u1, int kth) {
    unsigned lo = 0u, hi = 0xFFFFFFFFu;
    while (lo < hi) {
        unsigned mid = lo + ((hi - lo) >> 1);
        int cnt = __popcll(__ballot(u0 <= mid)) + __popcll(__ballot(u1 <= mid));
        if (cnt >= kth) hi = mid; else lo = mid + 1;
    }
    return hi;
}

// ---------- K1: pre-MLP + BN1 stats (32 thr/row, 1 ch/thr) ----------
__global__ __launch_bounds__(256) void k_pre(const float* __restrict__ x,
    const float* __restrict__ w1, const float* __restrict__ b1,
    const float* __restrict__ w2, const float* __restrict__ b2,
    float* __restrict__ h, float* __restrict__ stats)
{
    __shared__ float sw1[CIN * DD], sw2[DD * DD], sb1[DD], sb2[DD];
    __shared__ float bufx[RPB][20], buft[RPB][36];
    __shared__ float sstat[2 * DD];
    int tid = threadIdx.x;
    for (int t = tid; t < CIN * DD; t += 256) sw1[t] = w1[t];
    for (int t = tid; t < DD * DD; t += 256) sw2[t] = w2[t];
    if (tid < DD) { sb1[tid] = b1[tid]; sb2[tid] = b2[tid]; }
    if (tid < 2 * DD) sstat[tid] = 0.f;

    int r = tid >> 5, ch = tid & 31;
    int g = blockIdx.x * RPB + r;
    if (ch < CIN) bufx[r][ch] = x[(size_t)g * CIN + ch];
    __syncthreads();

    float acc = sb1[ch];
#pragma unroll
    for (int k4 = 0; k4 < CIN; k4 += 4) {
        float4 v = *(const float4*)&bufx[r][k4];
        acc = fmaf(v.x, sw1[(k4 + 0) * DD + ch], acc);
        acc = fmaf(v.y, sw1[(k4 + 1) * DD + ch], acc);
        acc = fmaf(v.z, sw1[(k4 + 2) * DD + ch], acc);
        acc = fmaf(v.w, sw1[(k4 + 3) * DD + ch], acc);
    }
    acc = elu_f(acc);
    buft[r][ch] = acc;
    __syncthreads();

    float o = sb2[ch];
#pragma unroll
    for (int k4 = 0; k4 < DD; k4 += 4) {
        float4 v = *(const float4*)&buft[r][k4];
        o = fmaf(v.x, sw2[(k4 + 0) * DD + ch], o);
        o = fmaf(v.y, sw2[(k4 + 1) * DD + ch], o);
        o = fmaf(v.z, sw2[(k4 + 2) * DD + ch], o);
        o = fmaf(v.w, sw2[(k4 + 3) * DD + ch], o);
    }
    o = elu_f(o);
    h[(size_t)g * DD + ch] = o;

    float s = o + __shfl_xor(o, 32);
    float q = o * o;
    q += __shfl_xor(q, 32);
    if ((tid & 32) == 0) { atomicAdd(&sstat[ch], s); atomicAdd(&sstat[DD + ch], q); }
    __syncthreads();
    if (tid < 2 * DD) atomicAdd(&ST(tid), sstat[tid]);
}

// ---------- K2: BN1 apply + h_l/s_l projections (32 thr/row) ----------
__global__ __launch_bounds__(256) void k_proj(const float* __restrict__ h,
    const float* __restrict__ stats,
    const float* __restrict__ g1, const float* __restrict__ b1g,
    const float* __restrict__ hw, const float* __restrict__ hb,
    const float* __restrict__ sw,
    float* __restrict__ xin, float* __restrict__ hl, float4* __restrict__ sl4)
{
    __shared__ float shw[DD * DD], ssw[DD * 3], sa[DD], sbp[DD], shb[DD];
    __shared__ float rrow[RPB][36];
    int tid = threadIdx.x;
    for (int t = tid; t < DD * DD; t += 256) shw[t] = hw[t];
    if (tid < DD * 3) ssw[tid] = sw[tid];
    if (tid < DD) {
        float mean = ST(tid) * (1.f / NPTS);
        float var = ST(32 + tid) * (1.f / NPTS) - mean * mean;
        float a = g1[tid] * rsqrtf(var + 1e-5f);
        sa[tid] = a;
        sbp[tid] = b1g[tid] - a * mean;
        shb[tid] = hb[tid];
    }
    __syncthreads();

    int r = tid >> 5, ch = tid & 31;
    int g = blockIdx.x * RPB + r;

    float v = fmaf(sa[ch], h[(size_t)g * DD + ch], sbp[ch]);
    xin[(size_t)g * DD + ch] = v;
    rrow[r][ch] = v;

    float p0 = v * ssw[ch * 3 + 0];
    float p1 = v * ssw[ch * 3 + 1];
    float p2 = v * ssw[ch * 3 + 2];
    p0 = grp_sum32(p0); p1 = grp_sum32(p1); p2 = grp_sum32(p2);
    if (ch == 0) sl4[g] = make_float4(p0, p1, p2, 0.5f * (p0 * p0 + p1 * p1 + p2 * p2));
    __syncthreads();

    float o = shb[ch];
#pragma unroll
    for (int k4 = 0; k4 < DD; k4 += 4) {
        float4 vv = *(const float4*)&rrow[r][k4];
        o = fmaf(vv.x, shw[(k4 + 0) * DD + ch], o);
        o = fmaf(vv.y, shw[(k4 + 1) * DD + ch], o);
        o = fmaf(vv.z, shw[(k4 + 2) * DD + ch], o);
        o = fmaf(vv.w, shw[(k4 + 3) * DD + ch], o);
    }
    hl[(size_t)g * DD + ch] = o;
}

// ---------- K3: kNN — global_load_lds staged quarters, 2 q/wave (r15 best) ---
__device__ __forceinline__ void select_emit(const float2* bufq, int C, int qidx,
    float qw, int lane, int* __restrict__ idxo, float* __restrict__ esq,
    float* __restrict__ sumd, float* __restrict__ indeg)
{
    float e0 = INFINITY, e1 = INFINITY;
    int j0 = -1, j1 = -1;
    if (lane < C) { float2 t = bufq[lane]; e0 = t.x; j0 = __float_as_int(t.y); }
    if (lane + 64 < C) { float2 t = bufq[lane + 64]; e1 = t.x; j1 = __float_as_int(t.y); }
    if (j0 == qidx) e0 = INFINITY;   // drop self
    if (j1 == qidx) e1 = INFINITY;
    unsigned u0 = fkey(e0), u1 = fkey(e1);
    unsigned thr = bisect_kth(u0, u1, KNN);
    unsigned long long ltm = (1ull << lane) - 1;
    unsigned long long mlt0 = __ballot(u0 < thr), mlt1 = __ballot(u1 < thr);
    unsigned long long meq0 = __ballot(u0 == thr), meq1 = __ballot(u1 == thr);
    int nlt = __popcll(mlt0) + __popcll(mlt1);
    int need = KNN - nlt;
    int rb = qidx * KNN;

    int pos = -1;
    if (u0 < thr) pos = __popcll(mlt0 & ltm);
    else if (u0 == thr) { int rk = __popcll(meq0 & ltm); if (rk < need) pos = nlt + rk; }
    if (pos >= 0) {
        float d2 = fmaxf(2.f * (e0 + qw), 0.f);
        idxo[rb + pos] = j0; esq[rb + pos] = d2;
        float dist = sqrtf(d2 + 1e-6f);
        atomicAdd(&sumd[j0], dist); atomicAdd(&indeg[j0], 1.f);
    }
    pos = -1;
    if (u1 < thr) pos = __popcll(mlt0) + __popcll(mlt1 & ltm);
    else if (u1 == thr) {
        int rk = __popcll(meq0) + __popcll(meq1 & ltm);
        if (rk < need) pos = nlt + rk;
    }
    if (pos >= 0) {
        float d2 = fmaxf(2.f * (e1 + qw), 0.f);
        idxo[rb + pos] = j1; esq[rb + pos] = d2;
        float dist = sqrtf(d2 + 1e-6f);
        atomicAdd(&sumd[j1], dist); atomicAdd(&indeg[j1], 1.f);
    }
}

typedef __attribute__((address_space(1))) const unsigned glds_src_t;
typedef __attribute__((address_space(3))) unsigned glds_dst_t;

__global__ __launch_bounds__(512, 4) void k_knn(const float4* __restrict__ sl4,
    int* __restrict__ idxo, float* __restrict__ esq,
    float* __restrict__ sumd, float* __restrict__ indeg)
{
    __shared__ float4 tile[2][QT];
    __shared__ float2 cand[KQPB][CAP];
    int tid = threadIdx.x, lane = tid & 63, w = tid >> 6;
    int qbase = blockIdx.x * KQPB;
    int qai = qbase + 2 * w, qbi = qai + 1;
    float4 qa4 = sl4[qai], qb4 = sl4[qbi];
    float qax = rfl(qa4.x), qay = rfl(qa4.y), qaz = rfl(qa4.z);
    float qbx = rfl(qb4.x), qby = rfl(qb4.y), qbz = rfl(qb4.z);

    // stage quarter qt into tile[b]: 4 async 1KB wave-DMAs, no VGPR dest
#define STAGE(qt, b) { \
    _Pragma("unroll") \
    for (int c = 0; c < 4; ++c) { \
        int off = w * 256 + c * 64; \
        __builtin_amdgcn_global_load_lds( \
            (glds_src_t*)(sl4 + (qt) * QT + off + lane), \
            (glds_dst_t*)&tile[b][off], 16, 0, 0); \
    } }

#define EDQ(p, ex, ey, ez) fmaf(-(ex), (p).x, fmaf(-(ey), (p).y, fmaf(-(ez), (p).z, (p).w)))

    // ================= pass 1: per-lane top-2 per query =================
    float m0a = INFINITY, m1a = INFINITY, m0b = INFINITY, m1b = INFINITY;
    STAGE(0, 0)
    __syncthreads();
    for (int t = 0; t < NQTR; ++t) {
        if (t + 1 < NQTR) STAGE(t + 1, (t + 1) & 1)
        const float4* tp = tile[t & 1];
#pragma unroll 4
        for (int i = 0; i < QT / 64; ++i) {
            float4 p = tp[i * 64 + lane];
            float ea = EDQ(p, qax, qay, qaz);
            float eb = EDQ(p, qbx, qby, qbz);
            float lo = fminf(ea, m0a), hi = fmaxf(ea, m0a);
            m0a = lo; m1a = fminf(m1a, hi);
            lo = fminf(eb, m0b); hi = fmaxf(eb, m0b);
            m0b = lo; m1b = fminf(m1b, hi);
        }
        __syncthreads();
    }
    float thra = kinv(bisect_kth(fkey(m0a), fkey(m1a), KNN + 1));
    float thrb = kinv(bisect_kth(fkey(m0b), fkey(m1b), KNN + 1));

    // ================= pass 2: collect candidates <= thr =================
    unsigned long long ltm = (1ull << lane) - 1;
    int ca = 0, cb = 0;
    float2* bufa = cand[2 * w];
    float2* bufb = cand[2 * w + 1];

#define COLL(e, thrv, cnt, brow, jj) { \
        unsigned long long mm = __ballot((e) <= (thrv)); \
        if (mm) { \
            if ((e) <= (thrv)) { \
                int pos = cnt + __popcll(mm & ltm); \
                if (pos < CAP) brow[pos] = make_float2((e), __int_as_float(jj)); \
            } \
            cnt += __popcll(mm); \
        } }

    STAGE(0, 0)
    __syncthreads();
    for (int t = 0; t < NQTR; ++t) {
        if (t + 1 < NQTR) STAGE(t + 1, (t + 1) & 1)
        const float4* tp = tile[t & 1];
        int tb = t * QT;
#pragma unroll 4
        for (int i = 0; i < QT / 64; ++i) {
            float4 p = tp[i * 64 + lane];
            int jj = tb + i * 64 + lane;
            float ea = EDQ(p, qax, qay, qaz);
            float eb = EDQ(p, qbx, qby, qbz);
            COLL(ea, thra, ca, bufa, jj)
            COLL(eb, thrb, cb, bufb, jj)
        }
        __syncthreads();
    }

    // ---- select: own wave's buffers (wave-local writes; no extra sync) ----
    select_emit(bufa, ca < CAP ? ca : CAP, qai, rfl(qa4.w), lane, idxo, esq, sumd, indeg);
    select_emit(bufb, cb < CAP ? cb : CAP, qbi, rfl(qb4.w), lane, idxo, esq, sumd, indeg);
}

// ---------- K4: gather + lin + post-MLP + BN2 stats + losses (32 thr/row) ----
__global__ __launch_bounds__(256) void k_agg(
    const int* __restrict__ idx, const float* __restrict__ esq,
    const float* __restrict__ hl, const float* __restrict__ xin,
    const float4* __restrict__ sl4,
    const float* __restrict__ sumd, const float* __restrict__ indeg,
    const float* __restrict__ lw, const float* __restrict__ lb,
    const float* __restrict__ pw1, const float* __restrict__ pb1,
    const float* __restrict__ pw2, const float* __restrict__ pb2,
    float* __restrict__ o, float* __restrict__ stats)
{
    __shared__ float slw[96 * DD], spw1[67 * DD], spw2[DD * DD];
    __shared__ float slb[DD], spb1[DD], spb2[DD];
    __shared__ float rbuf[RPB][100];   // [0,32) mean [32,64) max [64,96) xin [96,99) sl
    __shared__ float rb2[RPB][68];     // [0,32) xg  [32,64) o1
    __shared__ float sstat[2 * DD];
    __shared__ float sl1, sl2;
    int tid = threadIdx.x;
    for (int t = tid; t < 96 * DD; t += 256) slw[t] = lw[t];
    for (int t = tid; t < 67 * DD; t += 256) spw1[t] = pw1[t];
    for (int t = tid; t < DD * DD; t += 256) spw2[t] = pw2[t];
    if (tid < DD) { slb[tid] = lb[tid]; spb1[tid] = pb1[tid]; spb2[tid] = pb2[tid]; }
    if (tid < 2 * DD) sstat[tid] = 0.f;
    if (tid == 254) sl1 = 0.f;
    if (tid == 255) sl2 = 0.f;

    int r = tid >> 5, ch = tid & 31;
    int g = blockIdx.x * RPB + r;
    int rb = g * KNN;

    // ---- gather: this thread's channel over all 40 neighbors ----
    float sv = 0.f, mv = -INFINITY;
#pragma unroll 8
    for (int k = 0; k < KNN; ++k) {
        int j = idx[rb + k];
        float w = esq[rb + k];
        float m = hl[(size_t)j * DD + ch] * w;
        sv += m;
        mv = fmaxf(mv, m);
    }
    rbuf[r][ch] = sv * (1.f / KNN);
    rbuf[r][32 + ch] = mv;
    rbuf[r][64 + ch] = xin[(size_t)g * DD + ch];
    if (ch == 0) { float4 s = sl4[g]; rbuf[r][96] = s.x; rbuf[r][97] = s.y; rbuf[r][98] = s.z; }
    __syncthreads();

    // ---- per-edge losses, once per row ----
    float l2 = 0.f;
    {
        int j = idx[rb + ch];
        float w = esq[rb + ch];
        float dist = sqrtf(w + 1e-6f);
        float sd = sumd[j];
        float r1 = 1.f / (sd + 1e-4f);
        float dg = sd * r1 + 1e-4f;            // degs2[j] closed form
        float df = dist * r1 - dist / dg;
        l2 = df * df;
        if (ch < KNN - 32) {
            j = idx[rb + 32 + ch];
            w = esq[rb + 32 + ch];
            dist = sqrtf(w + 1e-6f);
            sd = sumd[j];
            r1 = 1.f / (sd + 1e-4f);
            dg = sd * r1 + 1e-4f;
            df = dist * r1 - dist / dg;
            l2 += df * df;
        }
    }
    l2 = grp_sum32(l2);
    if (ch == 0) {
        float id = indeg[g], sdg = sumd[g];
        float av = id > 0.f ? sdg / fmaxf(id, 1.f) : 0.f;
        float dd = av - 0.5f;
        atomicAdd(&sl2, l2);
        atomicAdd(&sl1, dd * dd);
    }

    // ---- GEMM1: xg = [mean|max|xin] @ lin_w + lin_b ----
    float acc = slb[ch];
#pragma unroll
    for (int k4 = 0; k4 < 96; k4 += 4) {
        float4 v = *(const float4*)&rbuf[r][k4];
        acc = fmaf(v.x, slw[(k4 + 0) * DD + ch], acc);
        acc = fmaf(v.y, slw[(k4 + 1) * DD + ch], acc);
        acc = fmaf(v.z, slw[(k4 + 2) * DD + ch], acc);
        acc = fmaf(v.w, slw[(k4 + 3) * DD + ch], acc);
    }
    rb2[r][ch] = acc;
    __syncthreads();

    // ---- GEMM2: o1 = elu([xg|s_l|xin] @ post_w1 + post_b1) ----
    acc = spb1[ch];
#pragma unroll
    for (int k4 = 0; k4 < DD; k4 += 4) {
        float4 v = *(const float4*)&rb2[r][k4];
        acc = fmaf(v.x, spw1[(k4 + 0) * DD + ch], acc);
        acc = fmaf(v.y, spw1[(k4 + 1) * DD + ch], acc);
        acc = fmaf(v.z, spw1[(k4 + 2) * DD + ch], acc);
        acc = fmaf(v.w, spw1[(k4 + 3) * DD + ch], acc);
    }
#pragma unroll
    for (int s2 = 0; s2 < 3; ++s2)
        acc = fmaf(rbuf[r][96 + s2], spw1[(32 + s2) * DD + ch], acc);
#pragma unroll
    for (int k4 = 0; k4 < DD; k4 += 4) {
        float4 v = *(const float4*)&rbuf[r][64 + k4];
        acc = fmaf(v.x, spw1[(35 + k4 + 0) * DD + ch], acc);
        acc = fmaf(v.y, spw1[(35 + k4 + 1) * DD + ch], acc);
        acc = fmaf(v.z, spw1[(35 + k4 + 2) * DD + ch], acc);
        acc = fmaf(v.w, spw1[(35 + k4 + 3) * DD + ch], acc);
    }
    acc = elu_f(acc);
    rb2[r][32 + ch] = acc;
    __syncthreads();

    // ---- GEMM3: o2 = elu(o1 @ post_w2 + post_b2) ----
    acc = spb2[ch];
#pragma unroll
    for (int k4 = 0; k4 < DD; k4 += 4) {
        float4 v = *(const float4*)&rb2[r][32 + k4];
        acc = fmaf(v.x, spw2[(k4 + 0) * DD + ch], acc);
        acc = fmaf(v.y, spw2[(k4 + 1) * DD + ch], acc);
        acc = fmaf(v.z, spw2[(k4 + 2) * DD + ch], acc);
        acc = fmaf(v.w, spw2[(k4 + 3) * DD + ch], acc);
    }
    acc = elu_f(acc);
    o[(size_t)g * DD + ch] = acc;

    // ---- BN2 stats ----
    float s = acc + __shfl_xor(acc, 32);
    float q = acc * acc;
    q += __shfl_xor(q, 32);
    if ((tid & 32) == 0) { atomicAdd(&sstat[ch], s); atomicAdd(&sstat[DD + ch], q); }
    __syncthreads();
    if (tid < 2 * DD) atomicAdd(&ST(64 + tid), sstat[tid]);
    if (tid == 0) { atomicAdd(&ST(128), sl1); atomicAdd(&ST(129), sl2); }
}

// ---------- K5: BN2 apply (float4) + loss writes ----------
__global__ __launch_bounds__(256) void k_out(const float* __restrict__ o,
    const float* __restrict__ stats, const float* __restrict__ g,
    const float* __restrict__ b, float* __restrict__ dout)
{
    __shared__ float sa[DD], sb[DD];
    int tid = threadIdx.x;
    if (tid < DD) {
        float mean = ST(64 + tid) * (1.f / NPTS);
        float var = ST(96 + tid) * (1.f / NPTS) - mean * mean;
        float a = g[tid] * rsqrtf(var + 1e-5f);
        sa[tid] = a;
        sb[tid] = b[tid] - a * mean;
    }
    __syncthreads();

    int t = blockIdx.x * 256 + tid;                 // float4 index over 65536
    float4 v = ((const float4*)o)[t];
    int cbase = (t * 4) & (DD - 1);
    float4 rr;
    rr.x = fmaf(sa[cbase + 0], v.x, sb[cbase + 0]);
    rr.y = fmaf(sa[cbase + 1], v.y, sb[cbase + 1]);
    rr.z = fmaf(sa[cbase + 2], v.z, sb[cbase + 2]);
    rr.w = fmaf(sa[cbase + 3], v.w, sb[cbase + 3]);
    ((float4*)dout)[t] = rr;

    if (blockIdx.x == 0) {
        if (tid == DD)     dout[NPTS * DD]     = 0.01f * ST(128) * (1.f / NPTS);
        if (tid == DD + 1) dout[NPTS * DD + 1] = 0.1f  * ST(129) * (1.f / ((float)NPTS * KNN));
    }
}

extern "C" void kernel_launch(void* const* d_in, const int* in_sizes, int n_in,
                              void* d_out, int out_size, void* d_ws, size_t ws_size,
                              hipStream_t stream)
{
    (void)in_sizes; (void)n_in; (void)out_size; (void)ws_size;
    const float* x      = (const float*)d_in[0];
    const float* pre_w1 = (const float*)d_in[5];
    const float* pre_b1 = (const float*)d_in[6];
    const float* pre_w2 = (const float*)d_in[7];
    const float* pre_b2 = (const float*)d_in[8];
    const float* bn1_g  = (const float*)d_in[9];
    const float* bn1_b  = (const float*)d_in[10];
    const float* lin_s_w = (const float*)d_in[11];
    const float* lin_h_w = (const float*)d_in[12];
    const float* lin_h_b = (const float*)d_in[13];
    const float* lin_w   = (const float*)d_in[14];
    const float* lin_b   = (const float*)d_in[15];
    const float* post_w1 = (const float*)d_in[16];
    const float* post_b1 = (const float*)d_in[17];
    const float* post_w2 = (const float*)d_in[18];
    const float* post_b2 = (const float*)d_in[19];
    const float* bn2_g   = (const float*)d_in[20];
    const float* bn2_b   = (const float*)d_in[21];

    float* W = (float*)d_ws;
    float* h     = W + OFF_H;
    float* xin   = W + OFF_XIN;
    float* hl    = W + OFF_HL;
    float4* sl4  = (float4*)(W + OFF_SL);
    float* esq   = W + OFF_ESQ;
    float* o     = W + OFF_O;
    int*   idx   = (int*)(W + OFF_IDX);
    float* sumd  = W + OFF_SUMD;
    float* indeg = W + OFF_INDEG;
    float* stats = W + OFF_STATS;
    float* dout  = (float*)d_out;

    hipMemsetAsync(W + OFF_SUMD, 0, ZERO_FLOATS * sizeof(float), stream);

    k_pre<<<NPTS / RPB, 256, 0, stream>>>(x, pre_w1, pre_b1, pre_w2, pre_b2, h, stats);
    k_proj<<<NPTS / RPB, 256, 0, stream>>>(h, stats, bn1_g, bn1_b,
                                           lin_h_w, lin_h_b, lin_s_w, xin, hl, sl4);
    k_knn<<<NPTS / KQPB, 512, 0, stream>>>(sl4, idx, esq, sumd, indeg);
    k_agg<<<NPTS / RPB, 256, 0, stream>>>(idx, esq, hl, xin, sl4, sumd, indeg,
                                          lin_w, lin_b, post_w1, post_b1, post_w2, post_b2,
                                          o, stats);
    k_out<<<NPTS * DD / 1024, 256, 0, stream>>>(o, stats, bn2_g, bn2_b, dout);
}

// Round 20
// 114.717 us; speedup vs baseline: 1.5803x; 1.0520x over previous
//
#include <hip/hip_runtime.h>
#include <math.h>

#define NPTS 8192
#define KNN 40
#define DD 32
#define CIN 16
#define RPB 8        // rows per block (32 threads per row)
#define KQPB 32      // kNN queries per block (2 per wave, 16 waves)
#define CAP 96       // kNN candidate buffer per query

// ---- ws layout (float offsets) ----
#define OFF_H      0u         // 8192*32
#define OFF_XIN    262144u    // 8192*32
#define OFF_HL     524288u    // 8192*32
#define OFF_SL     786432u    // 8192*4 (float4: s0,s1,s2, 0.5*|s|^2)
#define OFF_ESQ    819200u    // 8192*40
#define OFF_O      1146880u   // 8192*32
#define OFF_IDX    1409024u   // 8192*40 (int)
#define OFF_SUMD   1736704u   // 8192
#define OFF_INDEG  1744896u   // 8192
#define OFF_STATS  1753088u   // 130 slots x 32-float stride (1 line/slot)
#define ZERO_FLOATS (8192u + 8192u + 130u * 32u)

// slot map: 0..31 bn1 sum, 32..63 bn1 sq, 64..95 bn2 sum, 96..127 bn2 sq,
//           128 loss1, 129 loss2
#define ST(i) stats[(i) * 32]

__device__ __forceinline__ float elu_f(float x) { return x > 0.f ? x : (expf(x) - 1.f); }

__device__ __forceinline__ float grp_sum32(float v) {
#pragma unroll
    for (int m = 1; m < 32; m <<= 1) v += __shfl_xor(v, m);
    return v;
}

// wave-uniform float -> SGPR
__device__ __forceinline__ float rfl(float v) {
    return __int_as_float(__builtin_amdgcn_readfirstlane(__float_as_int(v)));
}

// order-preserving float->uint key
__device__ __forceinline__ unsigned fkey(float x) {
    unsigned b = __float_as_uint(x);
    return b ^ ((unsigned)((int)b >> 31) | 0x80000000u);
}
__device__ __forceinline__ float kinv(unsigned k) {
    unsigned b = (k & 0x80000000u) ? (k ^ 0x80000000u) : ~k;
    return __uint_as_float(b);
}

// kth-smallest (1-based) of the 128 values {u0,u1} x 64 lanes, exact
__device__ __forceinline__ unsigned bisect_kth(unsigned u0, unsigned u1, int kth) {
    unsigned lo = 0u, hi = 0xFFFFFFFFu;
    while (lo < hi) {
        unsigned mid = lo + ((hi - lo) >> 1);
        int cnt = __popcll(__ballot(u0 <= mid)) + __popcll(__ballot(u1 <= mid));
        if (cnt >= kth) hi = mid; else lo = mid + 1;
    }
    return hi;
}

// ---------- K1: pre-MLP + BN1 stats (32 thr/row, 1 ch/thr) ----------
__global__ __launch_bounds__(256) void k_pre(const float* __restrict__ x,
    const float* __restrict__ w1, const float* __restrict__ b1,
    const float* __restrict__ w2, const float* __restrict__ b2,
    float* __restrict__ h, float* __restrict__ stats)
{
    __shared__ float sw1[CIN * DD], sw2[DD * DD], sb1[DD], sb2[DD];
    __shared__ float bufx[RPB][20], buft[RPB][36];
    __shared__ float sstat[2 * DD];
    int tid = threadIdx.x;
    for (int t = tid; t < CIN * DD; t += 256) sw1[t] = w1[t];
    for (int t = tid; t < DD * DD; t += 256) sw2[t] = w2[t];
    if (tid < DD) { sb1[tid] = b1[tid]; sb2[tid] = b2[tid]; }
    if (tid < 2 * DD) sstat[tid] = 0.f;

    int r = tid >> 5, ch = tid & 31;
    int g = blockIdx.x * RPB + r;
    if (ch < CIN) bufx[r][ch] = x[(size_t)g * CIN + ch];
    __syncthreads();

    float acc = sb1[ch];
#pragma unroll
    for (int k4 = 0; k4 < CIN; k4 += 4) {
        float4 v = *(const float4*)&bufx[r][k4];
        acc = fmaf(v.x, sw1[(k4 + 0) * DD + ch], acc);
        acc = fmaf(v.y, sw1[(k4 + 1) * DD + ch], acc);
        acc = fmaf(v.z, sw1[(k4 + 2) * DD + ch], acc);
        acc = fmaf(v.w, sw1[(k4 + 3) * DD + ch], acc);
    }
    acc = elu_f(acc);
    buft[r][ch] = acc;
    __syncthreads();

    float o = sb2[ch];
#pragma unroll
    for (int k4 = 0; k4 < DD; k4 += 4) {
        float4 v = *(const float4*)&buft[r][k4];
        o = fmaf(v.x, sw2[(k4 + 0) * DD + ch], o);
        o = fmaf(v.y, sw2[(k4 + 1) * DD + ch], o);
        o = fmaf(v.z, sw2[(k4 + 2) * DD + ch], o);
        o = fmaf(v.w, sw2[(k4 + 3) * DD + ch], o);
    }
    o = elu_f(o);
    h[(size_t)g * DD + ch] = o;

    float s = o + __shfl_xor(o, 32);
    float q = o * o;
    q += __shfl_xor(q, 32);
    if ((tid & 32) == 0) { atomicAdd(&sstat[ch], s); atomicAdd(&sstat[DD + ch], q); }
    __syncthreads();
    if (tid < 2 * DD) atomicAdd(&ST(tid), sstat[tid]);
}

// ---------- K2: BN1 apply + h_l/s_l projections (32 thr/row) ----------
__global__ __launch_bounds__(256) void k_proj(const float* __restrict__ h,
    const float* __restrict__ stats,
    const float* __restrict__ g1, const float* __restrict__ b1g,
    const float* __restrict__ hw, const float* __restrict__ hb,
    const float* __restrict__ sw,
    float* __restrict__ xin, float* __restrict__ hl, float4* __restrict__ sl4)
{
    __shared__ float shw[DD * DD], ssw[DD * 3], sa[DD], sbp[DD], shb[DD];
    __shared__ float rrow[RPB][36];
    int tid = threadIdx.x;
    for (int t = tid; t < DD * DD; t += 256) shw[t] = hw[t];
    if (tid < DD * 3) ssw[tid] = sw[tid];
    if (tid < DD) {
        float mean = ST(tid) * (1.f / NPTS);
        float var = ST(32 + tid) * (1.f / NPTS) - mean * mean;
        float a = g1[tid] * rsqrtf(var + 1e-5f);
        sa[tid] = a;
        sbp[tid] = b1g[tid] - a * mean;
        shb[tid] = hb[tid];
    }
    __syncthreads();

    int r = tid >> 5, ch = tid & 31;
    int g = blockIdx.x * RPB + r;

    float v = fmaf(sa[ch], h[(size_t)g * DD + ch], sbp[ch]);
    xin[(size_t)g * DD + ch] = v;
    rrow[r][ch] = v;

    float p0 = v * ssw[ch * 3 + 0];
    float p1 = v * ssw[ch * 3 + 1];
    float p2 = v * ssw[ch * 3 + 2];
    p0 = grp_sum32(p0); p1 = grp_sum32(p1); p2 = grp_sum32(p2);
    if (ch == 0) sl4[g] = make_float4(p0, p1, p2, 0.5f * (p0 * p0 + p1 * p1 + p2 * p2));
    __syncthreads();

    float o = shb[ch];
#pragma unroll
    for (int k4 = 0; k4 < DD; k4 += 4) {
        float4 vv = *(const float4*)&rrow[r][k4];
        o = fmaf(vv.x, shw[(k4 + 0) * DD + ch], o);
        o = fmaf(vv.y, shw[(k4 + 1) * DD + ch], o);
        o = fmaf(vv.z, shw[(k4 + 2) * DD + ch], o);
        o = fmaf(vv.w, shw[(k4 + 3) * DD + ch], o);
    }
    hl[(size_t)g * DD + ch] = o;
}

// ---------- K3: kNN — ALL points LDS-resident, zero scan barriers ----------
// 1024-thread blocks (16 waves), 32 queries/block (2/wave), grid 256 = 1
// block/CU. Stage all 8192 points (128KB) into LDS once via global_load_lds,
// ONE barrier, then pass 1 (top-2 + exact 41st threshold) and pass 2
// (ballot-prefix collect) scan LDS with NO barriers, no DMA drains, no
// lockstep. Selection semantics identical to r15 (exact, tie-ranked).
__device__ __forceinline__ void select_emit(const float2* bufq, int C, int qidx,
    float qw, int lane, int* __restrict__ idxo, float* __restrict__ esq,
    float* __restrict__ sumd, float* __restrict__ indeg)
{
    float e0 = INFINITY, e1 = INFINITY;
    int j0 = -1, j1 = -1;
    if (lane < C) { float2 t = bufq[lane]; e0 = t.x; j0 = __float_as_int(t.y); }
    if (lane + 64 < C) { float2 t = bufq[lane + 64]; e1 = t.x; j1 = __float_as_int(t.y); }
    if (j0 == qidx) e0 = INFINITY;   // drop self
    if (j1 == qidx) e1 = INFINITY;
    unsigned u0 = fkey(e0), u1 = fkey(e1);
    unsigned thr = bisect_kth(u0, u1, KNN);
    unsigned long long ltm = (1ull << lane) - 1;
    unsigned long long mlt0 = __ballot(u0 < thr), mlt1 = __ballot(u1 < thr);
    unsigned long long meq0 = __ballot(u0 == thr), meq1 = __ballot(u1 == thr);
    int nlt = __popcll(mlt0) + __popcll(mlt1);
    int need = KNN - nlt;
    int rb = qidx * KNN;

    int pos = -1;
    if (u0 < thr) pos = __popcll(mlt0 & ltm);
    else if (u0 == thr) { int rk = __popcll(meq0 & ltm); if (rk < need) pos = nlt + rk; }
    if (pos >= 0) {
        float d2 = fmaxf(2.f * (e0 + qw), 0.f);
        idxo[rb + pos] = j0; esq[rb + pos] = d2;
        float dist = sqrtf(d2 + 1e-6f);
        atomicAdd(&sumd[j0], dist); atomicAdd(&indeg[j0], 1.f);
    }
    pos = -1;
    if (u1 < thr) pos = __popcll(mlt0) + __popcll(mlt1 & ltm);
    else if (u1 == thr) {
        int rk = __popcll(meq0) + __popcll(meq1 & ltm);
        if (rk < need) pos = nlt + rk;
    }
    if (pos >= 0) {
        float d2 = fmaxf(2.f * (e1 + qw), 0.f);
        idxo[rb + pos] = j1; esq[rb + pos] = d2;
        float dist = sqrtf(d2 + 1e-6f);
        atomicAdd(&sumd[j1], dist); atomicAdd(&indeg[j1], 1.f);
    }
}

typedef __attribute__((address_space(1))) const unsigned glds_src_t;
typedef __attribute__((address_space(3))) unsigned glds_dst_t;

#define EDQ(p, ex, ey, ez) fmaf(-(ex), (p).x, fmaf(-(ey), (p).y, fmaf(-(ez), (p).z, (p).w)))

__global__ __launch_bounds__(1024, 4) void k_knn(const float4* __restrict__ sl4,
    int* __restrict__ idxo, float* __restrict__ esq,
    float* __restrict__ sumd, float* __restrict__ indeg)
{
    __shared__ float4 tile[NPTS];                 // 128KB: all points
    __shared__ float2 cand[KQPB][CAP];            // 24KB
    int tid = threadIdx.x, lane = tid & 63, w = tid >> 6;
    int qbase = blockIdx.x * KQPB;
    int qai = qbase + 2 * w, qbi = qai + 1;
    float4 qa4 = sl4[qai], qb4 = sl4[qbi];
    float qax = rfl(qa4.x), qay = rfl(qa4.y), qaz = rfl(qa4.z);
    float qbx = rfl(qb4.x), qby = rfl(qb4.y), qbz = rfl(qb4.z);

    // ---- stage ALL points once: 8 async 1KB wave-DMAs per wave ----
#pragma unroll
    for (int k = 0; k < NPTS / 1024; ++k) {
        int off = k * 1024 + w * 64;
        __builtin_amdgcn_global_load_lds(
            (glds_src_t*)(sl4 + off + lane),
            (glds_dst_t*)&tile[off], 16, 0, 0);
    }
    __syncthreads();                               // the ONLY barrier

    // ================= pass 1: per-lane top-2 per query (no barriers) ======
    float m0a = INFINITY, m1a = INFINITY, m0b = INFINITY, m1b = INFINITY;
#pragma unroll 4
    for (int i = 0; i < NPTS / 64; ++i) {
        float4 p = tile[i * 64 + lane];
        float ea = EDQ(p, qax, qay, qaz);
        float eb = EDQ(p, qbx, qby, qbz);
        float lo = fminf(ea, m0a), hi = fmaxf(ea, m0a);
        m0a = lo; m1a = fminf(m1a, hi);
        lo = fminf(eb, m0b); hi = fmaxf(eb, m0b);
        m0b = lo; m1b = fminf(m1b, hi);
    }
    float thra = kinv(bisect_kth(fkey(m0a), fkey(m1a), KNN + 1));
    float thrb = kinv(bisect_kth(fkey(m0b), fkey(m1b), KNN + 1));

    // ================= pass 2: collect candidates <= thr (no barriers) =====
    unsigned long long ltm = (1ull << lane) - 1;
    int ca = 0, cb = 0;
    float2* bufa = cand[2 * w];
    float2* bufb = cand[2 * w + 1];

#define COLL(e, thrv, cnt, brow, jj) { \
        unsigned long long mm = __ballot((e) <= (thrv)); \
        if (mm) { \
            if ((e) <= (thrv)) { \
                int pos = cnt + __popcll(mm & ltm); \
                if (pos < CAP) brow[pos] = make_float2((e), __int_as_float(jj)); \
            } \
            cnt += __popcll(mm); \
        } }

#pragma unroll 4
    for (int i = 0; i < NPTS / 64; ++i) {
        float4 p = tile[i * 64 + lane];
        int jj = i * 64 + lane;
        float ea = EDQ(p, qax, qay, qaz);
        float eb = EDQ(p, qbx, qby, qbz);
        COLL(ea, thra, ca, bufa, jj)
        COLL(eb, thrb, cb, bufb, jj)
    }

    // ---- select: own wave's buffers (wave-local; no sync needed) ----
    select_emit(bufa, ca < CAP ? ca : CAP, qai, rfl(qa4.w), lane, idxo, esq, sumd, indeg);
    select_emit(bufb, cb < CAP ? cb : CAP, qbi, rfl(qb4.w), lane, idxo, esq, sumd, indeg);
}

// ---------- K4: gather + lin + post-MLP + BN2 stats + losses (32 thr/row) ----
__global__ __launch_bounds__(256) void k_agg(
    const int* __restrict__ idx, const float* __restrict__ esq,
    const float* __restrict__ hl, const float* __restrict__ xin,
    const float4* __restrict__ sl4,
    const float* __restrict__ sumd, const float* __restrict__ indeg,
    const float* __restrict__ lw, const float* __restrict__ lb,
    const float* __restrict__ pw1, const float* __restrict__ pb1,
    const float* __restrict__ pw2, const float* __restrict__ pb2,
    float* __restrict__ o, float* __restrict__ stats)
{
    __shared__ float slw[96 * DD], spw1[67 * DD], spw2[DD * DD];
    __shared__ float slb[DD], spb1[DD], spb2[DD];
    __shared__ float rbuf[RPB][100];   // [0,32) mean [32,64) max [64,96) xin [96,99) sl
    __shared__ float rb2[RPB][68];     // [0,32) xg  [32,64) o1
    __shared__ float sstat[2 * DD];
    __shared__ float sl1, sl2;
    int tid = threadIdx.x;
    for (int t = tid; t < 96 * DD; t += 256) slw[t] = lw[t];
    for (int t = tid; t < 67 * DD; t += 256) spw1[t] = pw1[t];
    for (int t = tid; t < DD * DD; t += 256) spw2[t] = pw2[t];
    if (tid < DD) { slb[tid] = lb[tid]; spb1[tid] = pb1[tid]; spb2[tid] = pb2[tid]; }
    if (tid < 2 * DD) sstat[tid] = 0.f;
    if (tid == 254) sl1 = 0.f;
    if (tid == 255) sl2 = 0.f;

    int r = tid >> 5, ch = tid & 31;
    int g = blockIdx.x * RPB + r;
    int rb = g * KNN;

    // ---- gather: this thread's channel over all 40 neighbors ----
    float sv = 0.f, mv = -INFINITY;
#pragma unroll 8
    for (int k = 0; k < KNN; ++k) {
        int j = idx[rb + k];
        float w = esq[rb + k];
        float m = hl[(size_t)j * DD + ch] * w;
        sv += m;
        mv = fmaxf(mv, m);
    }
    rbuf[r][ch] = sv * (1.f / KNN);
    rbuf[r][32 + ch] = mv;
    rbuf[r][64 + ch] = xin[(size_t)g * DD + ch];
    if (ch == 0) { float4 s = sl4[g]; rbuf[r][96] = s.x; rbuf[r][97] = s.y; rbuf[r][98] = s.z; }
    __syncthreads();

    // ---- per-edge losses, once per row ----
    float l2 = 0.f;
    {
        int j = idx[rb + ch];
        float w = esq[rb + ch];
        float dist = sqrtf(w + 1e-6f);
        float sd = sumd[j];
        float r1 = 1.f / (sd + 1e-4f);
        float dg = sd * r1 + 1e-4f;            // degs2[j] closed form
        float df = dist * r1 - dist / dg;
        l2 = df * df;
        if (ch < KNN - 32) {
            j = idx[rb + 32 + ch];
            w = esq[rb + 32 + ch];
            dist = sqrtf(w + 1e-6f);
            sd = sumd[j];
            r1 = 1.f / (sd + 1e-4f);
            dg = sd * r1 + 1e-4f;
            df = dist * r1 - dist / dg;
            l2 += df * df;
        }
    }
    l2 = grp_sum32(l2);
    if (ch == 0) {
        float id = indeg[g], sdg = sumd[g];
        float av = id > 0.f ? sdg / fmaxf(id, 1.f) : 0.f;
        float dd = av - 0.5f;
        atomicAdd(&sl2, l2);
        atomicAdd(&sl1, dd * dd);
    }

    // ---- GEMM1: xg = [mean|max|xin] @ lin_w + lin_b ----
    float acc = slb[ch];
#pragma unroll
    for (int k4 = 0; k4 < 96; k4 += 4) {
        float4 v = *(const float4*)&rbuf[r][k4];
        acc = fmaf(v.x, slw[(k4 + 0) * DD + ch], acc);
        acc = fmaf(v.y, slw[(k4 + 1) * DD + ch], acc);
        acc = fmaf(v.z, slw[(k4 + 2) * DD + ch], acc);
        acc = fmaf(v.w, slw[(k4 + 3) * DD + ch], acc);
    }
    rb2[r][ch] = acc;
    __syncthreads();

    // ---- GEMM2: o1 = elu([xg|s_l|xin] @ post_w1 + post_b1) ----
    acc = spb1[ch];
#pragma unroll
    for (int k4 = 0; k4 < DD; k4 += 4) {
        float4 v = *(const float4*)&rb2[r][k4];
        acc = fmaf(v.x, spw1[(k4 + 0) * DD + ch], acc);
        acc = fmaf(v.y, spw1[(k4 + 1) * DD + ch], acc);
        acc = fmaf(v.z, spw1[(k4 + 2) * DD + ch], acc);
        acc = fmaf(v.w, spw1[(k4 + 3) * DD + ch], acc);
    }
#pragma unroll
    for (int s2 = 0; s2 < 3; ++s2)
        acc = fmaf(rbuf[r][96 + s2], spw1[(32 + s2) * DD + ch], acc);
#pragma unroll
    for (int k4 = 0; k4 < DD; k4 += 4) {
        float4 v = *(const float4*)&rbuf[r][64 + k4];
        acc = fmaf(v.x, spw1[(35 + k4 + 0) * DD + ch], acc);
        acc = fmaf(v.y, spw1[(35 + k4 + 1) * DD + ch], acc);
        acc = fmaf(v.z, spw1[(35 + k4 + 2) * DD + ch], acc);
        acc = fmaf(v.w, spw1[(35 + k4 + 3) * DD + ch], acc);
    }
    acc = elu_f(acc);
    rb2[r][32 + ch] = acc;
    __syncthreads();

    // ---- GEMM3: o2 = elu(o1 @ post_w2 + post_b2) ----
    acc = spb2[ch];
#pragma unroll
    for (int k4 = 0; k4 < DD; k4 += 4) {
        float4 v = *(const float4*)&rb2[r][32 + k4];
        acc = fmaf(v.x, spw2[(k4 + 0) * DD + ch], acc);
        acc = fmaf(v.y, spw2[(k4 + 1) * DD + ch], acc);
        acc = fmaf(v.z, spw2[(k4 + 2) * DD + ch], acc);
        acc = fmaf(v.w, spw2[(k4 + 3) * DD + ch], acc);
    }
    acc = elu_f(acc);
    o[(size_t)g * DD + ch] = acc;

    // ---- BN2 stats ----
    float s = acc + __shfl_xor(acc, 32);
    float q = acc * acc;
    q += __shfl_xor(q, 32);
    if ((tid & 32) == 0) { atomicAdd(&sstat[ch], s); atomicAdd(&sstat[DD + ch], q); }
    __syncthreads();
    if (tid < 2 * DD) atomicAdd(&ST(64 + tid), sstat[tid]);
    if (tid == 0) { atomicAdd(&ST(128), sl1); atomicAdd(&ST(129), sl2); }
}

// ---------- K5: BN2 apply (float4) + loss writes ----------
__global__ __launch_bounds__(256) void k_out(const float* __restrict__ o,
    const float* __restrict__ stats, const float* __restrict__ g,
    const float* __restrict__ b, float* __restrict__ dout)
{
    __shared__ float sa[DD], sb[DD];
    int tid = threadIdx.x;
    if (tid < DD) {
        float mean = ST(64 + tid) * (1.f / NPTS);
        float var = ST(96 + tid) * (1.f / NPTS) - mean * mean;
        float a = g[tid] * rsqrtf(var + 1e-5f);
        sa[tid] = a;
        sb[tid] = b[tid] - a * mean;
    }
    __syncthreads();

    int t = blockIdx.x * 256 + tid;                 // float4 index over 65536
    float4 v = ((const float4*)o)[t];
    int cbase = (t * 4) & (DD - 1);
    float4 rr;
    rr.x = fmaf(sa[cbase + 0], v.x, sb[cbase + 0]);
    rr.y = fmaf(sa[cbase + 1], v.y, sb[cbase + 1]);
    rr.z = fmaf(sa[cbase + 2], v.z, sb[cbase + 2]);
    rr.w = fmaf(sa[cbase + 3], v.w, sb[cbase + 3]);
    ((float4*)dout)[t] = rr;

    if (blockIdx.x == 0) {
        if (tid == DD)     dout[NPTS * DD]     = 0.01f * ST(128) * (1.f / NPTS);
        if (tid == DD + 1) dout[NPTS * DD + 1] = 0.1f  * ST(129) * (1.f / ((float)NPTS * KNN));
    }
}

extern "C" void kernel_launch(void* const* d_in, const int* in_sizes, int n_in,
                              void* d_out, int out_size, void* d_ws, size_t ws_size,
                              hipStream_t stream)
{
    (void)in_sizes; (void)n_in; (void)out_size; (void)ws_size;
    const float* x      = (const float*)d_in[0];
    const float* pre_w1 = (const float*)d_in[5];
    const float* pre_b1 = (const float*)d_in[6];
    const float* pre_w2 = (const float*)d_in[7];
    const float* pre_b2 = (const float*)d_in[8];
    const float* bn1_g  = (const float*)d_in[9];
    const float* bn1_b  = (const float*)d_in[10];
    const float* lin_s_w = (const float*)d_in[11];
    const float* lin_h_w = (const float*)d_in[12];
    const float* lin_h_b = (const float*)d_in[13];
    const float* lin_w   = (const float*)d_in[14];
    const float* lin_b   = (const float*)d_in[15];
    const float* post_w1 = (const float*)d_in[16];
    const float* post_b1 = (const float*)d_in[17];
    const float* post_w2 = (const float*)d_in[18];
    const float* post_b2 = (const float*)d_in[19];
    const float* bn2_g   = (const float*)d_in[20];
    const float* bn2_b   = (const float*)d_in[21];

    float* W = (float*)d_ws;
    float* h     = W + OFF_H;
    float* xin   = W + OFF_XIN;
    float* hl    = W + OFF_HL;
    float4* sl4  = (float4*)(W + OFF_SL);
    float* esq   = W + OFF_ESQ;
    float* o     = W + OFF_O;
    int*   idx   = (int*)(W + OFF_IDX);
    float* sumd  = W + OFF_SUMD;
    float* indeg = W + OFF_INDEG;
    float* stats = W + OFF_STATS;
    float* dout  = (float*)d_out;

    hipMemsetAsync(W + OFF_SUMD, 0, ZERO_FLOATS * sizeof(float), stream);

    k_pre<<<NPTS / RPB, 256, 0, stream>>>(x, pre_w1, pre_b1, pre_w2, pre_b2, h, stats);
    k_proj<<<NPTS / RPB, 256, 0, stream>>>(h, stats, bn1_g, bn1_b,
                                           lin_h_w, lin_h_b, lin_s_w, xin, hl, sl4);
    k_knn<<<NPTS / KQPB, 1024, 0, stream>>>(sl4, idx, esq, sumd, indeg);
    k_agg<<<NPTS / RPB, 256, 0, stream>>>(idx, esq, hl, xin, sl4, sumd, indeg,
                                          lin_w, lin_b, post_w1, post_b1, post_w2, post_b2,
                                          o, stats);
    k_out<<<NPTS * DD / 1024, 256, 0, stream>>>(o, stats, bn2_g, bn2_b, dout);
}